// Round 12
// baseline (1032.143 us; speedup 1.0000x reference)
//
#include <hip/hip_runtime.h>
#include <stdint.h>

typedef unsigned short u16;
typedef __attribute__((ext_vector_type(4))) float f32x4;
typedef __attribute__((ext_vector_type(8))) __bf16 bf16x8;
typedef __attribute__((ext_vector_type(8))) unsigned short u16x8;

__device__ __forceinline__ u16 f2bf(float f) {
  unsigned u = __builtin_bit_cast(unsigned, f);
  u = (u + 0x7fffu + ((u >> 16) & 1u)) >> 16;
  return (u16)u;
}

typedef __attribute__((address_space(1))) const void gvoid_t;
typedef __attribute__((address_space(3))) void lvoid_t;

__device__ __forceinline__ void gload_lds16(const void* g, void* l) {
  __builtin_amdgcn_global_load_lds((gvoid_t*)g, (lvoid_t*)l, 16, 0, 0);
}

// ---------------- dequant: w[row][k] = (q[row][k] - z[row][k/128]) * s[row][k/128], bf16
__global__ __launch_bounds__(256)
void dequant_kernel(const int* __restrict__ q, const float* __restrict__ s,
                    const int* __restrict__ z, u16* __restrict__ w, int K) {
  const int row = blockIdx.y;
  const int k = (blockIdx.x * 256 + threadIdx.x) << 3;
  const int ng = K >> 7;
  const int g = k >> 7;
  const float sv = s[(size_t)row * ng + g];
  const float zv = (float)z[(size_t)row * ng + g];
  const int4* qp = (const int4*)(q + (size_t)row * K + k);
  const int4 a = qp[0], b = qp[1];
  u16x8 o;
  o[0] = f2bf(((float)a.x - zv) * sv);
  o[1] = f2bf(((float)a.y - zv) * sv);
  o[2] = f2bf(((float)a.z - zv) * sv);
  o[3] = f2bf(((float)a.w - zv) * sv);
  o[4] = f2bf(((float)b.x - zv) * sv);
  o[5] = f2bf(((float)b.y - zv) * sv);
  o[6] = f2bf(((float)b.z - zv) * sv);
  o[7] = f2bf(((float)b.w - zv) * sv);
  *reinterpret_cast<u16x8*>(w + (size_t)row * K + k) = o;
}

// ---------------- fp32 -> bf16 bulk convert (x)
__global__ __launch_bounds__(256)
void cvt_kernel(const float* __restrict__ in, u16* __restrict__ out) {
  const size_t i = ((size_t)blockIdx.x * 256 + threadIdx.x) << 3;
  const float4* p = (const float4*)(in + i);
  const float4 a = p[0], b = p[1];
  u16x8 o;
  o[0] = f2bf(a.x); o[1] = f2bf(a.y); o[2] = f2bf(a.z); o[3] = f2bf(a.w);
  o[4] = f2bf(b.x); o[5] = f2bf(b.y); o[6] = f2bf(b.z); o[7] = f2bf(b.w);
  *reinterpret_cast<u16x8*>(out + i) = o;
}

// ---------------- 256x256 GEMM v10: v9 + pre-issued ph1 reads + NT epilogue stores
// C = A * B^T (bf16, K-major). 512 thr = 8 waves (2M x 4N); per-wave 128x64; BK=64.
// Tile T (buf p=T&1, other q); {b1,a1} of T were PRE-ISSUED in T-1's ph4:
//   ph1: BARO; lgkm(0)[pre-issued b1,a1 — drained under prev MFMA4]; stg A(T+1)h0->q;
//        MFMA(a1,b1); issue {b2,a2,a4,a3} pinned order
//   ph2: BARO; lgkm(8)[b2,a2]; stg A(T+1)h1->q; MFMA(a2,b1)
//   ph3: BARO; lgkm(4)[+a4]; stg B(T+2)h0->p; MFMA(a4,b2); GATE vmcnt(2)
//        [queue 10 = B(T+1)4,A(T+1)4,B(T+2)h0 2 -> completes next tile's 8 inputs]
//   ph4: BARO; lgkm(0)[+a3]; stg B(T+2)h1->p; MFMA(a3,b2);
//        pre-issue next {b1,a1} from q  [safe: BARO4 follows ALL waves' ph3 gates
//        -> A(T+1),B(T+1) landed globally; b1/a1 regs dead since ph2]
// NT stores: C streams bypass/evict-first L3 -> L3 retains B panels (the 988MB
// GEMM1 over-fetch was C-write eviction of B; GEMM2 same code ran 2.3x faster
// per-tile purely because its inputs stayed L3-resident).
template<bool RELU2>
__global__ __launch_bounds__(512, 2)
void gemm256(const u16* __restrict__ Ap, const u16* __restrict__ Bp,
             void* __restrict__ Cptr, int M, int N, int K) {
  __shared__ __align__(16) u16 As[2][256][64];
  __shared__ __align__(16) u16 Bs[2][256][64];
  const int tid = threadIdx.x;
  const int lane = tid & 63;
  const int wid = tid >> 6;
  const int wr = wid >> 2, wc = wid & 3;

  const int nbx = N >> 8;
  const int nwg = gridDim.x;
  int bid = blockIdx.x;
  bid = (bid & 7) * (nwg >> 3) + (bid >> 3);   // XCD swizzle (nwg % 8 == 0)
  const int m0 = (bid / nbx) << 8;             // n-fastest (R6 order)
  const int n0 = (bid % nbx) << 8;

  const int srow = tid >> 3;        // staging row within 64-row sweep
  const int scol = tid & 7;         // staging 16B segment
  const int lr = lane & 15;
  const int lk = (lane >> 4) << 3;
  const int xorc = (lr & 7) << 3;   // read-side swizzle (row&7 == lr&7)

  // ds_read bases: row base per (array, buf); k byte-offset koff0 / koff0^64
  const char* baA0 = (const char*)&As[0][0][0] + (wr * 128 + lr) * 128;
  const char* baA1 = baA0 + 32768;
  const char* baB0 = (const char*)&Bs[0][0][0] + (wc * 64 + lr) * 128;
  const char* baB1 = baB0 + 32768;
  const int koff0 = (lk ^ xorc) * 2;

  f32x4 acc[8][4] = {};
  bf16x8 a1[4], a2[4], a3[4], a4[4], b1[4], b2[4];

  const int nk = K >> 6;

#define STG_A(bufi, h, kt) do { _Pragma("unroll") \
  for (int l_ = 0; l_ < 2; ++l_) { \
    const int r_ = (h) * 128 + l_ * 64 + srow; \
    gload_lds16(Ap + (size_t)(m0 + r_) * K + (size_t)((kt) << 6) + ((scol ^ (srow & 7)) << 3), \
                &As[bufi][r_][scol << 3]); } } while (0)
#define STG_B(bufi, h, kt) do { _Pragma("unroll") \
  for (int l_ = 0; l_ < 2; ++l_) { \
    const int r_ = (h) * 128 + l_ * 64 + srow; \
    gload_lds16(Bp + (size_t)(n0 + r_) * K + (size_t)((kt) << 6) + ((scol ^ (srow & 7)) << 3), \
                &Bs[bufi][r_][scol << 3]); } } while (0)
// base+imm reads: A rows (half*4+i)*16 -> imm (half*4+i)*2048; ks1 byte = koff0^64
#define RD_A(base, ks, half, dst) do { _Pragma("unroll") \
  for (int i_ = 0; i_ < 4; ++i_) \
    dst[i_] = *reinterpret_cast<const bf16x8*>( \
      (base) + ((half) * 4 + i_) * 2048 + (koff0 ^ ((ks) * 64))); } while (0)
#define RD_B(base, ks, dst) do { _Pragma("unroll") \
  for (int j_ = 0; j_ < 4; ++j_) \
    dst[j_] = *reinterpret_cast<const bf16x8*>( \
      (base) + j_ * 2048 + (koff0 ^ ((ks) * 64))); } while (0)
#define MFMA16(ASET, BSET, I0) do { _Pragma("unroll") \
  for (int i_ = 0; i_ < 4; ++i_) { _Pragma("unroll") \
    for (int j_ = 0; j_ < 4; ++j_) \
      acc[(I0) + i_][j_] = __builtin_amdgcn_mfma_f32_16x16x32_bf16( \
        ASET[i_], BSET[j_], acc[(I0) + i_][j_], 0, 0, 0); } } while (0)
#define BARO() do { asm volatile("" ::: "memory"); __builtin_amdgcn_s_barrier(); \
  asm volatile("" ::: "memory"); } while (0)
#define LGKM(n) do { asm volatile("s_waitcnt lgkmcnt(" #n ")" ::: "memory"); \
  __builtin_amdgcn_sched_barrier(0); } while (0)
#define SB0 __builtin_amdgcn_sched_barrier(0)
#define GATE2 asm volatile("s_waitcnt vmcnt(2)" ::: "memory")
#define PRIO(Q) do { __builtin_amdgcn_s_setprio(1); Q; __builtin_amdgcn_s_setprio(0); } while (0)
// One K-tile. bA/bB = bases for buf p; bAn/bBn = next tile's buf q (pre-issue).
#define TILE4(bA, bB, bAn, bBn, SA1, SA2, SB3, SB4) do { \
  BARO(); \
  LGKM(0); \
  SA1; \
  PRIO(MFMA16(a1, b1, 0)); \
  SB0; RD_B(bB, 1, b2); SB0; RD_A(bA, 0, 1, a2); SB0; RD_A(bA, 1, 1, a4); SB0; RD_A(bA, 1, 0, a3); \
  BARO(); \
  LGKM(8); \
  SA2; \
  PRIO(MFMA16(a2, b1, 4)); \
  BARO(); \
  LGKM(4); \
  SB3; \
  PRIO(MFMA16(a4, b2, 4)); \
  GATE2; \
  BARO(); \
  LGKM(0); \
  SB4; \
  PRIO(MFMA16(a3, b2, 0)); \
  SB0; RD_B(bBn, 0, b1); SB0; RD_A(bAn, 0, 0, a1); \
} while (0)

  // prologue: A(0),B(0)->buf0, B(1)->buf1 (12 loads); vmcnt(4) leaves B(1) in flight
  STG_A(0, 0, 0); STG_A(0, 1, 0);
  STG_B(0, 0, 0); STG_B(0, 1, 0);
  STG_B(1, 0, 1); STG_B(1, 1, 1);
  asm volatile("s_waitcnt vmcnt(4)" ::: "memory");
  BARO();
  // pre-issue tile 0's {b1,a1}
  SB0; RD_B(baB0, 0, b1); SB0; RD_A(baA0, 0, 0, a1);

  const int nit = nk >> 1;
  for (int it = 0; it < nit; ++it) {
    const int t1 = 2 * it + 1;
    int t2 = 2 * it + 2; if (t2 >= nk) t2 -= nk;   // wrap: tail stages are dummies
    int t3 = 2 * it + 3; if (t3 >= nk) t3 -= nk;
    // tile 2it (buf0): stage A(t1)->buf1, B(t2)->buf0; pre-issue tile t1 reads (buf1)
    TILE4(baA0, baB0, baA1, baB1,
          STG_A(1, 0, t1), STG_A(1, 1, t1), STG_B(0, 0, t2), STG_B(0, 1, t2));
    // tile t1 (buf1): stage A(t2)->buf0, B(t3)->buf1; pre-issue tile t2 reads (buf0)
    TILE4(baA1, baB1, baA0, baB0,
          STG_A(0, 0, t2), STG_A(0, 1, t2), STG_B(1, 0, t3), STG_B(1, 1, t3));
  }
  asm volatile("s_waitcnt vmcnt(0) lgkmcnt(0)" ::: "memory");  // drain dummies before epilogue

  // epilogue: C/D layout col = lane&15, row = (lane>>4)*4 + reg  [m89-verified]
  // NT stores: keep C streams from evicting B panels out of L3.
  const int crow = (lane >> 4) << 2;
  const int ccol = lane & 15;
#pragma unroll
  for (int i = 0; i < 8; ++i) {
#pragma unroll
    for (int j = 0; j < 4; ++j) {
#pragma unroll
      for (int q = 0; q < 4; ++q) {
        const int m = m0 + wr * 128 + i * 16 + crow + q;
        const int n = n0 + wc * 64 + j * 16 + ccol;
        const float v = acc[i][j][q];
        if constexpr (RELU2) {
          const float r = fmaxf(v, 0.f);
          __builtin_nontemporal_store(f2bf(r * r), (u16*)Cptr + (size_t)m * N + n);
        } else {
          __builtin_nontemporal_store(v, (float*)Cptr + (size_t)m * N + n);
        }
      }
    }
  }
#undef STG_A
#undef STG_B
#undef RD_A
#undef RD_B
#undef MFMA16
#undef BARO
#undef LGKM
#undef SB0
#undef GATE2
#undef PRIO
#undef TILE4
}

extern "C" void kernel_launch(void* const* d_in, const int* in_sizes, int n_in,
                              void* d_out, int out_size, void* d_ws, size_t ws_size,
                              hipStream_t stream) {
  const float* x    = (const float*)d_in[0];
  const int*   q_up = (const int*)d_in[1];
  const float* s_up = (const float*)d_in[2];
  const int*   z_up = (const int*)d_in[3];
  const int*   q_dn = (const int*)d_in[4];
  const float* s_dn = (const float*)d_in[5];
  const int*   z_dn = (const int*)d_in[6];
  float* y = (float*)d_out;

  const int H = 4096, I = 14336;
  const int M = in_sizes[0] / H;  // 4096 tokens

  const size_t wbytes = (size_t)I * H * 2;   // 117.4 MB bf16 weight buffer (reused)
  const size_t abytes = (size_t)M * I * 2;   // 117.4 MB bf16 activations
  const size_t xbytes = (size_t)M * H * 2;   // 33.5 MB bf16 x
  u16* wbuf = (u16*)d_ws;
  u16* abuf = (u16*)((char*)d_ws + wbytes);
  u16* xbf  = (u16*)((char*)d_ws + wbytes + abytes);
  if (ws_size < wbytes + abytes + xbytes) return;  // insufficient scratch: fail cleanly

  // 1. dequant W_up [I, H] -> bf16
  dequant_kernel<<<dim3(H / 8 / 256, I), 256, 0, stream>>>(q_up, s_up, z_up, wbuf, H);
  // 1b. x -> bf16
  cvt_kernel<<<dim3((int)(((size_t)M * H) >> 11)), 256, 0, stream>>>(x, xbf);
  // 2. a = relu(x @ W_up^T)^2, bf16   (grid 896 % 8 == 0)
  gemm256<true><<<dim3((M / 256) * (I / 256)), 512, 0, stream>>>(xbf, wbuf, abuf, M, I, H);
  // 3. dequant W_down [H, I] -> bf16
  dequant_kernel<<<dim3(I / 8 / 256, H), 256, 0, stream>>>(q_dn, s_dn, z_dn, wbuf, I);
  // 4. y = a @ W_down^T, fp32   (grid 256 % 8 == 0)
  gemm256<false><<<dim3((M / 256) * (H / 256)), 512, 0, stream>>>(abuf, wbuf, y, M, H, I);
}

// Round 13
// 995.133 us; speedup vs baseline: 1.0372x; 1.0372x over previous
//
#include <hip/hip_runtime.h>
#include <stdint.h>

typedef unsigned short u16;
typedef __attribute__((ext_vector_type(4))) float f32x4;
typedef __attribute__((ext_vector_type(8))) __bf16 bf16x8;
typedef __attribute__((ext_vector_type(8))) unsigned short u16x8;

__device__ __forceinline__ u16 f2bf(float f) {
  unsigned u = __builtin_bit_cast(unsigned, f);
  u = (u + 0x7fffu + ((u >> 16) & 1u)) >> 16;
  return (u16)u;
}

typedef __attribute__((address_space(1))) const void gvoid_t;
typedef __attribute__((address_space(3))) void lvoid_t;

__device__ __forceinline__ void gload_lds16(const void* g, void* l) {
  __builtin_amdgcn_global_load_lds((gvoid_t*)g, (lvoid_t*)l, 16, 0, 0);
}

// ---------------- dequant: w[row][k] = (q[row][k] - z[row][k/128]) * s[row][k/128], bf16
__global__ __launch_bounds__(256)
void dequant_kernel(const int* __restrict__ q, const float* __restrict__ s,
                    const int* __restrict__ z, u16* __restrict__ w, int K) {
  const int row = blockIdx.y;
  const int k = (blockIdx.x * 256 + threadIdx.x) << 3;
  const int ng = K >> 7;
  const int g = k >> 7;
  const float sv = s[(size_t)row * ng + g];
  const float zv = (float)z[(size_t)row * ng + g];
  const int4* qp = (const int4*)(q + (size_t)row * K + k);
  const int4 a = qp[0], b = qp[1];
  u16x8 o;
  o[0] = f2bf(((float)a.x - zv) * sv);
  o[1] = f2bf(((float)a.y - zv) * sv);
  o[2] = f2bf(((float)a.z - zv) * sv);
  o[3] = f2bf(((float)a.w - zv) * sv);
  o[4] = f2bf(((float)b.x - zv) * sv);
  o[5] = f2bf(((float)b.y - zv) * sv);
  o[6] = f2bf(((float)b.z - zv) * sv);
  o[7] = f2bf(((float)b.w - zv) * sv);
  *reinterpret_cast<u16x8*>(w + (size_t)row * K + k) = o;
}

// ---------------- fp32 -> bf16 bulk convert (x)
__global__ __launch_bounds__(256)
void cvt_kernel(const float* __restrict__ in, u16* __restrict__ out) {
  const size_t i = ((size_t)blockIdx.x * 256 + threadIdx.x) << 3;
  const float4* p = (const float4*)(in + i);
  const float4 a = p[0], b = p[1];
  u16x8 o;
  o[0] = f2bf(a.x); o[1] = f2bf(a.y); o[2] = f2bf(a.z); o[3] = f2bf(a.w);
  o[4] = f2bf(b.x); o[5] = f2bf(b.y); o[6] = f2bf(b.z); o[7] = f2bf(b.w);
  *reinterpret_cast<u16x8*>(out + i) = o;
}

// ---------------- 256x256 GEMM v11: v9 counted-lgkm + pre-issued ph1 reads (NO NT stores)
// C = A * B^T (bf16, K-major). 512 thr = 8 waves (2M x 4N); per-wave 128x64; BK=64.
// Tile T (buf p=T&1, other q); {b1,a1} of T were PRE-ISSUED in T-1's ph4
// (drain under prev MFMA4 + gate + barrier -> ph1's lgkm(0) is nearly free):
//   ph1: BARO; lgkm(0); stg A(T+1)h0->q; MFMA(a1,b1); issue {b2,a2,a4,a3} pinned
//   ph2: BARO; lgkm(8)[b2,a2]; stg A(T+1)h1->q; MFMA(a2,b1)
//   ph3: BARO; lgkm(4)[+a4]; stg B(T+2)h0->p; MFMA(a4,b2); GATE vmcnt(2)
//        [queue 10 = B(T+1)4 + A(T+1)4 + B(T+2)h0 2 -> completes next tile's 8 inputs]
//   ph4: BARO; lgkm(0)[+a3]; stg B(T+2)h1->p; MFMA(a3,b2);
//        pre-issue next {b1,a1} from q  [sound: BARO4 follows ALL waves' ph3 gates]
// R12 lesson: NT stores -> 2.2x write amplification (2B scalar stores defeat
// write-combining); plain stores here. R11 lesson: counted lgkm + sound ledger
// was the win (952); this isolates the pre-issue delta.
template<bool RELU2>
__global__ __launch_bounds__(512, 2)
void gemm256(const u16* __restrict__ Ap, const u16* __restrict__ Bp,
             void* __restrict__ Cptr, int M, int N, int K) {
  __shared__ __align__(16) u16 As[2][256][64];
  __shared__ __align__(16) u16 Bs[2][256][64];
  const int tid = threadIdx.x;
  const int lane = tid & 63;
  const int wid = tid >> 6;
  const int wr = wid >> 2, wc = wid & 3;

  const int nbx = N >> 8;
  const int nwg = gridDim.x;
  int bid = blockIdx.x;
  bid = (bid & 7) * (nwg >> 3) + (bid >> 3);   // XCD swizzle (nwg % 8 == 0)
  const int m0 = (bid / nbx) << 8;             // n-fastest (R6 order)
  const int n0 = (bid % nbx) << 8;

  const int srow = tid >> 3;        // staging row within 64-row sweep
  const int scol = tid & 7;         // staging 16B segment
  const int lr = lane & 15;
  const int lk = (lane >> 4) << 3;
  const int xorc = (lr & 7) << 3;   // read-side swizzle (row&7 == lr&7)

  // ds_read bases: row base per (array, buf); k byte-offset koff0 / koff0^64
  const char* baA0 = (const char*)&As[0][0][0] + (wr * 128 + lr) * 128;
  const char* baA1 = baA0 + 32768;
  const char* baB0 = (const char*)&Bs[0][0][0] + (wc * 64 + lr) * 128;
  const char* baB1 = baB0 + 32768;
  const int koff0 = (lk ^ xorc) * 2;

  f32x4 acc[8][4] = {};
  bf16x8 a1[4], a2[4], a3[4], a4[4], b1[4], b2[4];

  const int nk = K >> 6;

#define STG_A(bufi, h, kt) do { _Pragma("unroll") \
  for (int l_ = 0; l_ < 2; ++l_) { \
    const int r_ = (h) * 128 + l_ * 64 + srow; \
    gload_lds16(Ap + (size_t)(m0 + r_) * K + (size_t)((kt) << 6) + ((scol ^ (srow & 7)) << 3), \
                &As[bufi][r_][scol << 3]); } } while (0)
#define STG_B(bufi, h, kt) do { _Pragma("unroll") \
  for (int l_ = 0; l_ < 2; ++l_) { \
    const int r_ = (h) * 128 + l_ * 64 + srow; \
    gload_lds16(Bp + (size_t)(n0 + r_) * K + (size_t)((kt) << 6) + ((scol ^ (srow & 7)) << 3), \
                &Bs[bufi][r_][scol << 3]); } } while (0)
// base+imm reads: A rows (half*4+i)*16 -> imm (half*4+i)*2048; ks1 byte = koff0^64
#define RD_A(base, ks, half, dst) do { _Pragma("unroll") \
  for (int i_ = 0; i_ < 4; ++i_) \
    dst[i_] = *reinterpret_cast<const bf16x8*>( \
      (base) + ((half) * 4 + i_) * 2048 + (koff0 ^ ((ks) * 64))); } while (0)
#define RD_B(base, ks, dst) do { _Pragma("unroll") \
  for (int j_ = 0; j_ < 4; ++j_) \
    dst[j_] = *reinterpret_cast<const bf16x8*>( \
      (base) + j_ * 2048 + (koff0 ^ ((ks) * 64))); } while (0)
#define MFMA16(ASET, BSET, I0) do { _Pragma("unroll") \
  for (int i_ = 0; i_ < 4; ++i_) { _Pragma("unroll") \
    for (int j_ = 0; j_ < 4; ++j_) \
      acc[(I0) + i_][j_] = __builtin_amdgcn_mfma_f32_16x16x32_bf16( \
        ASET[i_], BSET[j_], acc[(I0) + i_][j_], 0, 0, 0); } } while (0)
#define BARO() do { asm volatile("" ::: "memory"); __builtin_amdgcn_s_barrier(); \
  asm volatile("" ::: "memory"); } while (0)
#define LGKM(n) do { asm volatile("s_waitcnt lgkmcnt(" #n ")" ::: "memory"); \
  __builtin_amdgcn_sched_barrier(0); } while (0)
#define SB0 __builtin_amdgcn_sched_barrier(0)
#define GATE2 asm volatile("s_waitcnt vmcnt(2)" ::: "memory")
#define PRIO(Q) do { __builtin_amdgcn_s_setprio(1); Q; __builtin_amdgcn_s_setprio(0); } while (0)
// One K-tile. bA/bB = bases for buf p; bAn/bBn = next tile's buf q (pre-issue).
#define TILE4(bA, bB, bAn, bBn, SA1, SA2, SB3, SB4) do { \
  BARO(); \
  LGKM(0); \
  SA1; \
  PRIO(MFMA16(a1, b1, 0)); \
  SB0; RD_B(bB, 1, b2); SB0; RD_A(bA, 0, 1, a2); SB0; RD_A(bA, 1, 1, a4); SB0; RD_A(bA, 1, 0, a3); \
  BARO(); \
  LGKM(8); \
  SA2; \
  PRIO(MFMA16(a2, b1, 4)); \
  BARO(); \
  LGKM(4); \
  SB3; \
  PRIO(MFMA16(a4, b2, 4)); \
  GATE2; \
  BARO(); \
  LGKM(0); \
  SB4; \
  PRIO(MFMA16(a3, b2, 0)); \
  SB0; RD_B(bBn, 0, b1); SB0; RD_A(bAn, 0, 0, a1); \
} while (0)

  // prologue: A(0),B(0)->buf0, B(1)->buf1 (12 loads); vmcnt(4) leaves B(1) in flight
  STG_A(0, 0, 0); STG_A(0, 1, 0);
  STG_B(0, 0, 0); STG_B(0, 1, 0);
  STG_B(1, 0, 1); STG_B(1, 1, 1);
  asm volatile("s_waitcnt vmcnt(4)" ::: "memory");
  BARO();
  // pre-issue tile 0's {b1,a1} (sound: BARO follows all waves' vmcnt(4))
  SB0; RD_B(baB0, 0, b1); SB0; RD_A(baA0, 0, 0, a1);

  const int nit = nk >> 1;
  for (int it = 0; it < nit; ++it) {
    const int t1 = 2 * it + 1;
    int t2 = 2 * it + 2; if (t2 >= nk) t2 -= nk;   // wrap: tail stages are dummies
    int t3 = 2 * it + 3; if (t3 >= nk) t3 -= nk;
    // tile 2it (buf0): stage A(t1)->buf1, B(t2)->buf0; pre-issue tile t1 reads (buf1)
    TILE4(baA0, baB0, baA1, baB1,
          STG_A(1, 0, t1), STG_A(1, 1, t1), STG_B(0, 0, t2), STG_B(0, 1, t2));
    // tile t1 (buf1): stage A(t2)->buf0, B(t3)->buf1; pre-issue tile t2 reads (buf0)
    TILE4(baA1, baB1, baA0, baB0,
          STG_A(0, 0, t2), STG_A(0, 1, t2), STG_B(1, 0, t3), STG_B(1, 1, t3));
  }
  asm volatile("s_waitcnt vmcnt(0) lgkmcnt(0)" ::: "memory");  // drain dummies before epilogue

  // epilogue: C/D layout col = lane&15, row = (lane>>4)*4 + reg  [m89-verified]
  // Plain stores (R12 lesson: NT 2-byte stores -> 2.2x write amplification).
  const int crow = (lane >> 4) << 2;
  const int ccol = lane & 15;
#pragma unroll
  for (int i = 0; i < 8; ++i) {
#pragma unroll
    for (int j = 0; j < 4; ++j) {
#pragma unroll
      for (int q = 0; q < 4; ++q) {
        const int m = m0 + wr * 128 + i * 16 + crow + q;
        const int n = n0 + wc * 64 + j * 16 + ccol;
        const float v = acc[i][j][q];
        if constexpr (RELU2) {
          const float r = fmaxf(v, 0.f);
          ((u16*)Cptr)[(size_t)m * N + n] = f2bf(r * r);
        } else {
          ((float*)Cptr)[(size_t)m * N + n] = v;
        }
      }
    }
  }
#undef STG_A
#undef STG_B
#undef RD_A
#undef RD_B
#undef MFMA16
#undef BARO
#undef LGKM
#undef SB0
#undef GATE2
#undef PRIO
#undef TILE4
}

extern "C" void kernel_launch(void* const* d_in, const int* in_sizes, int n_in,
                              void* d_out, int out_size, void* d_ws, size_t ws_size,
                              hipStream_t stream) {
  const float* x    = (const float*)d_in[0];
  const int*   q_up = (const int*)d_in[1];
  const float* s_up = (const float*)d_in[2];
  const int*   z_up = (const int*)d_in[3];
  const int*   q_dn = (const int*)d_in[4];
  const float* s_dn = (const float*)d_in[5];
  const int*   z_dn = (const int*)d_in[6];
  float* y = (float*)d_out;

  const int H = 4096, I = 14336;
  const int M = in_sizes[0] / H;  // 4096 tokens

  const size_t wbytes = (size_t)I * H * 2;   // 117.4 MB bf16 weight buffer (reused)
  const size_t abytes = (size_t)M * I * 2;   // 117.4 MB bf16 activations
  const size_t xbytes = (size_t)M * H * 2;   // 33.5 MB bf16 x
  u16* wbuf = (u16*)d_ws;
  u16* abuf = (u16*)((char*)d_ws + wbytes);
  u16* xbf  = (u16*)((char*)d_ws + wbytes + abytes);
  if (ws_size < wbytes + abytes + xbytes) return;  // insufficient scratch: fail cleanly

  // 1. dequant W_up [I, H] -> bf16
  dequant_kernel<<<dim3(H / 8 / 256, I), 256, 0, stream>>>(q_up, s_up, z_up, wbuf, H);
  // 1b. x -> bf16
  cvt_kernel<<<dim3((int)(((size_t)M * H) >> 11)), 256, 0, stream>>>(x, xbf);
  // 2. a = relu(x @ W_up^T)^2, bf16   (grid 896 % 8 == 0)
  gemm256<true><<<dim3((M / 256) * (I / 256)), 512, 0, stream>>>(xbf, wbuf, abuf, M, I, H);
  // 3. dequant W_down [H, I] -> bf16
  dequant_kernel<<<dim3(I / 8 / 256, H), 256, 0, stream>>>(q_dn, s_dn, z_dn, wbuf, I);
  // 4. y = a @ W_down^T, fp32   (grid 256 % 8 == 0)
  gemm256<false><<<dim3((M / 256) * (H / 256)), 512, 0, stream>>>(abuf, wbuf, y, M, H, I);
}

// Round 14
// 957.471 us; speedup vs baseline: 1.0780x; 1.0393x over previous
//
#include <hip/hip_runtime.h>
#include <stdint.h>

typedef unsigned short u16;
typedef __attribute__((ext_vector_type(4))) float f32x4;
typedef __attribute__((ext_vector_type(8))) __bf16 bf16x8;
typedef __attribute__((ext_vector_type(8))) unsigned short u16x8;

__device__ __forceinline__ u16 f2bf(float f) {
  unsigned u = __builtin_bit_cast(unsigned, f);
  u = (u + 0x7fffu + ((u >> 16) & 1u)) >> 16;
  return (u16)u;
}

typedef __attribute__((address_space(1))) const void gvoid_t;
typedef __attribute__((address_space(3))) void lvoid_t;

__device__ __forceinline__ void gload_lds16(const void* g, void* l) {
  __builtin_amdgcn_global_load_lds((gvoid_t*)g, (lvoid_t*)l, 16, 0, 0);
}

// ---------------- dequant: w[row][k] = (q[row][k] - z[row][k/128]) * s[row][k/128], bf16
__global__ __launch_bounds__(256)
void dequant_kernel(const int* __restrict__ q, const float* __restrict__ s,
                    const int* __restrict__ z, u16* __restrict__ w, int K) {
  const int row = blockIdx.y;
  const int k = (blockIdx.x * 256 + threadIdx.x) << 3;
  const int ng = K >> 7;
  const int g = k >> 7;
  const float sv = s[(size_t)row * ng + g];
  const float zv = (float)z[(size_t)row * ng + g];
  const int4* qp = (const int4*)(q + (size_t)row * K + k);
  const int4 a = qp[0], b = qp[1];
  u16x8 o;
  o[0] = f2bf(((float)a.x - zv) * sv);
  o[1] = f2bf(((float)a.y - zv) * sv);
  o[2] = f2bf(((float)a.z - zv) * sv);
  o[3] = f2bf(((float)a.w - zv) * sv);
  o[4] = f2bf(((float)b.x - zv) * sv);
  o[5] = f2bf(((float)b.y - zv) * sv);
  o[6] = f2bf(((float)b.z - zv) * sv);
  o[7] = f2bf(((float)b.w - zv) * sv);
  *reinterpret_cast<u16x8*>(w + (size_t)row * K + k) = o;
}

// ---------------- fp32 -> bf16 bulk convert (x)
__global__ __launch_bounds__(256)
void cvt_kernel(const float* __restrict__ in, u16* __restrict__ out) {
  const size_t i = ((size_t)blockIdx.x * 256 + threadIdx.x) << 3;
  const float4* p = (const float4*)(in + i);
  const float4 a = p[0], b = p[1];
  u16x8 o;
  o[0] = f2bf(a.x); o[1] = f2bf(a.y); o[2] = f2bf(a.z); o[3] = f2bf(a.w);
  o[4] = f2bf(b.x); o[5] = f2bf(b.y); o[6] = f2bf(b.z); o[7] = f2bf(b.w);
  *reinterpret_cast<u16x8*>(out + i) = o;
}

// ---------------- 256x256 GEMM v12: R11 counted-lgkm base + merged ph3/ph4 (3 barriers/tile)
// C = A * B^T (bf16, K-major). 512 thr = 8 waves (2M x 4N); per-wave 128x64; BK=64.
// Tile T (buf p=T&1, other q):
//   ph1: BARO; rd{b1,a1}; lgkm(0); stg A(T+1)h0->q; MFMA(a1,b1);
//        issue {b2,a2,a4,a3} pinned order (SB0-separated)
//   ph2: BARO; lgkm(8)[b2,a2 done; a4,a3 drain under MFMA]; stg A(T+1)h1->q; MFMA(a2,b1)
//   ph3: BARO; lgkm(0)[+a4,a3]; stg B(T+2)h0+h1->p; MFMA(a4,b2)+MFMA(a3,b2) [32];
//        GATE vmcnt(4)
// Stage-safety: B(T+2)->p.B overwrites regions whose b2 reads drained at each
// wave's ph2 lgkm(8) (b2 first in the pinned queue), which precedes BARO(ph3) —
// all waves ✓. A(T+1)->q.A: q.A reads drained prev tile's ph3 lgkm(0) < BARO(ph1) ✓.
// Gate chain: prev gate left B(T+1)[4]; this tile adds A(T+1)[4]+B(T+2)[4] -> 12;
// vmcnt(4) completes B(T+1)+A(T+1) = exactly next tile's inputs, leaves B(T+2).
// Counted-vmcnt never 0 in loop (T4). Prologue: A(0),B(0),B(1); vmcnt(4) leaves B(1).
// R12/R13 lessons: NT stores = 2.2x write amplification; pre-issued ph1 reads = -43us.
template<bool RELU2>
__global__ __launch_bounds__(512, 2)
void gemm256(const u16* __restrict__ Ap, const u16* __restrict__ Bp,
             void* __restrict__ Cptr, int M, int N, int K) {
  __shared__ __align__(16) u16 As[2][256][64];
  __shared__ __align__(16) u16 Bs[2][256][64];
  const int tid = threadIdx.x;
  const int lane = tid & 63;
  const int wid = tid >> 6;
  const int wr = wid >> 2, wc = wid & 3;

  const int nbx = N >> 8;
  const int nwg = gridDim.x;
  int bid = blockIdx.x;
  bid = (bid & 7) * (nwg >> 3) + (bid >> 3);   // XCD swizzle (nwg % 8 == 0)
  const int m0 = (bid / nbx) << 8;             // n-fastest (R6 order)
  const int n0 = (bid % nbx) << 8;

  const int srow = tid >> 3;        // staging row within 64-row sweep
  const int scol = tid & 7;         // staging 16B segment
  const int lr = lane & 15;
  const int lk = (lane >> 4) << 3;
  const int xorc = (lr & 7) << 3;   // read-side swizzle (row&7 == lr&7)

  // ds_read bases: row base per (array, buf); k byte-offset koff0 / koff0^64
  const char* baA0 = (const char*)&As[0][0][0] + (wr * 128 + lr) * 128;
  const char* baA1 = baA0 + 32768;
  const char* baB0 = (const char*)&Bs[0][0][0] + (wc * 64 + lr) * 128;
  const char* baB1 = baB0 + 32768;
  const int koff0 = (lk ^ xorc) * 2;

  f32x4 acc[8][4] = {};
  bf16x8 a1[4], a2[4], a3[4], a4[4], b1[4], b2[4];

  const int nk = K >> 6;

#define STG_A(bufi, h, kt) do { _Pragma("unroll") \
  for (int l_ = 0; l_ < 2; ++l_) { \
    const int r_ = (h) * 128 + l_ * 64 + srow; \
    gload_lds16(Ap + (size_t)(m0 + r_) * K + (size_t)((kt) << 6) + ((scol ^ (srow & 7)) << 3), \
                &As[bufi][r_][scol << 3]); } } while (0)
#define STG_B(bufi, h, kt) do { _Pragma("unroll") \
  for (int l_ = 0; l_ < 2; ++l_) { \
    const int r_ = (h) * 128 + l_ * 64 + srow; \
    gload_lds16(Bp + (size_t)(n0 + r_) * K + (size_t)((kt) << 6) + ((scol ^ (srow & 7)) << 3), \
                &Bs[bufi][r_][scol << 3]); } } while (0)
// base+imm reads: A rows (half*4+i)*16 -> imm (half*4+i)*2048; ks1 byte = koff0^64
#define RD_A(base, ks, half, dst) do { _Pragma("unroll") \
  for (int i_ = 0; i_ < 4; ++i_) \
    dst[i_] = *reinterpret_cast<const bf16x8*>( \
      (base) + ((half) * 4 + i_) * 2048 + (koff0 ^ ((ks) * 64))); } while (0)
#define RD_B(base, ks, dst) do { _Pragma("unroll") \
  for (int j_ = 0; j_ < 4; ++j_) \
    dst[j_] = *reinterpret_cast<const bf16x8*>( \
      (base) + j_ * 2048 + (koff0 ^ ((ks) * 64))); } while (0)
#define MFMA16(ASET, BSET, I0) do { _Pragma("unroll") \
  for (int i_ = 0; i_ < 4; ++i_) { _Pragma("unroll") \
    for (int j_ = 0; j_ < 4; ++j_) \
      acc[(I0) + i_][j_] = __builtin_amdgcn_mfma_f32_16x16x32_bf16( \
        ASET[i_], BSET[j_], acc[(I0) + i_][j_], 0, 0, 0); } } while (0)
#define BARO() do { asm volatile("" ::: "memory"); __builtin_amdgcn_s_barrier(); \
  asm volatile("" ::: "memory"); } while (0)
#define LGKM(n) do { asm volatile("s_waitcnt lgkmcnt(" #n ")" ::: "memory"); \
  __builtin_amdgcn_sched_barrier(0); } while (0)
#define SB0 __builtin_amdgcn_sched_barrier(0)
#define GATE4 asm volatile("s_waitcnt vmcnt(4)" ::: "memory")
#define PRIO(Q) do { __builtin_amdgcn_s_setprio(1); Q; __builtin_amdgcn_s_setprio(0); } while (0)
// One K-tile, 3 phases. bA/bB = bases for buf p. SA1/SA2 = A(T+1) halves (->q);
// SB3/SB4 = B(T+2) halves (->p, both in ph3).
#define TILE3(bA, bB, SA1, SA2, SB3, SB4) do { \
  BARO(); \
  RD_B(bB, 0, b1); RD_A(bA, 0, 0, a1); \
  LGKM(0); \
  SA1; \
  PRIO(MFMA16(a1, b1, 0)); \
  SB0; RD_B(bB, 1, b2); SB0; RD_A(bA, 0, 1, a2); SB0; RD_A(bA, 1, 1, a4); SB0; RD_A(bA, 1, 0, a3); \
  BARO(); \
  LGKM(8); \
  SA2; \
  PRIO(MFMA16(a2, b1, 4)); \
  BARO(); \
  LGKM(0); \
  SB3; SB4; \
  PRIO(MFMA16(a4, b2, 4); MFMA16(a3, b2, 0)); \
  GATE4; \
} while (0)

  // prologue: A(0),B(0)->buf0, B(1)->buf1 (12 loads); vmcnt(4) leaves B(1) in flight
  STG_A(0, 0, 0); STG_A(0, 1, 0);
  STG_B(0, 0, 0); STG_B(0, 1, 0);
  STG_B(1, 0, 1); STG_B(1, 1, 1);
  asm volatile("s_waitcnt vmcnt(4)" ::: "memory");

  const int nit = nk >> 1;
  for (int it = 0; it < nit; ++it) {
    const int t1 = 2 * it + 1;
    int t2 = 2 * it + 2; if (t2 >= nk) t2 -= nk;   // wrap: tail stages are dummies
    int t3 = 2 * it + 3; if (t3 >= nk) t3 -= nk;
    // tile 2it (buf0): stage A(t1)->buf1, B(t2)->buf0
    TILE3(baA0, baB0, STG_A(1, 0, t1), STG_A(1, 1, t1), STG_B(0, 0, t2), STG_B(0, 1, t2));
    // tile t1 (buf1): stage A(t2)->buf0, B(t3)->buf1
    TILE3(baA1, baB1, STG_A(0, 0, t2), STG_A(0, 1, t2), STG_B(1, 0, t3), STG_B(1, 1, t3));
  }
  asm volatile("s_waitcnt vmcnt(0) lgkmcnt(0)" ::: "memory");  // drain dummies before epilogue

  // epilogue: C/D layout col = lane&15, row = (lane>>4)*4 + reg  [m89-verified]
  // Plain stores (R12 lesson: NT 2-byte stores -> 2.2x write amplification).
  const int crow = (lane >> 4) << 2;
  const int ccol = lane & 15;
#pragma unroll
  for (int i = 0; i < 8; ++i) {
#pragma unroll
    for (int j = 0; j < 4; ++j) {
#pragma unroll
      for (int q = 0; q < 4; ++q) {
        const int m = m0 + wr * 128 + i * 16 + crow + q;
        const int n = n0 + wc * 64 + j * 16 + ccol;
        const float v = acc[i][j][q];
        if constexpr (RELU2) {
          const float r = fmaxf(v, 0.f);
          ((u16*)Cptr)[(size_t)m * N + n] = f2bf(r * r);
        } else {
          ((float*)Cptr)[(size_t)m * N + n] = v;
        }
      }
    }
  }
#undef STG_A
#undef STG_B
#undef RD_A
#undef RD_B
#undef MFMA16
#undef BARO
#undef LGKM
#undef SB0
#undef GATE4
#undef PRIO
#undef TILE3
}

extern "C" void kernel_launch(void* const* d_in, const int* in_sizes, int n_in,
                              void* d_out, int out_size, void* d_ws, size_t ws_size,
                              hipStream_t stream) {
  const float* x    = (const float*)d_in[0];
  const int*   q_up = (const int*)d_in[1];
  const float* s_up = (const float*)d_in[2];
  const int*   z_up = (const int*)d_in[3];
  const int*   q_dn = (const int*)d_in[4];
  const float* s_dn = (const float*)d_in[5];
  const int*   z_dn = (const int*)d_in[6];
  float* y = (float*)d_out;

  const int H = 4096, I = 14336;
  const int M = in_sizes[0] / H;  // 4096 tokens

  const size_t wbytes = (size_t)I * H * 2;   // 117.4 MB bf16 weight buffer (reused)
  const size_t abytes = (size_t)M * I * 2;   // 117.4 MB bf16 activations
  const size_t xbytes = (size_t)M * H * 2;   // 33.5 MB bf16 x
  u16* wbuf = (u16*)d_ws;
  u16* abuf = (u16*)((char*)d_ws + wbytes);
  u16* xbf  = (u16*)((char*)d_ws + wbytes + abytes);
  if (ws_size < wbytes + abytes + xbytes) return;  // insufficient scratch: fail cleanly

  // 1. dequant W_up [I, H] -> bf16
  dequant_kernel<<<dim3(H / 8 / 256, I), 256, 0, stream>>>(q_up, s_up, z_up, wbuf, H);
  // 1b. x -> bf16
  cvt_kernel<<<dim3((int)(((size_t)M * H) >> 11)), 256, 0, stream>>>(x, xbf);
  // 2. a = relu(x @ W_up^T)^2, bf16   (grid 896 % 8 == 0)
  gemm256<true><<<dim3((M / 256) * (I / 256)), 512, 0, stream>>>(xbf, wbuf, abuf, M, I, H);
  // 3. dequant W_down [H, I] -> bf16
  dequant_kernel<<<dim3(I / 8 / 256, H), 256, 0, stream>>>(q_dn, s_dn, z_dn, wbuf, I);
  // 4. y = a @ W_down^T, fp32   (grid 256 % 8 == 0)
  gemm256<false><<<dim3((M / 256) * (H / 256)), 512, 0, stream>>>(abuf, wbuf, y, M, H, I);
}